// Round 5
// baseline (4373.476 us; speedup 1.0000x reference)
//
#include <hip/hip_runtime.h>

#define NN 100000
#define NE 1600000
#define NB 256    // dst buckets
#define BSZ 391   // nodes per bucket (255*391=99705; bucket 255 holds 295)
#define EB 782    // edge blocks of 2048
#define NRG 8     // src ranges for phased gather
#define RSZ 12500 // range size (8*12500 = NN exact)

typedef __attribute__((ext_vector_type(8))) short short8;
typedef __attribute__((ext_vector_type(4))) float floatx4;

__device__ __forceinline__ unsigned short f2bf(float f) {
  unsigned u = __float_as_uint(f);
  u += 0x7fffu + ((u >> 16) & 1u);  // RNE
  return (unsigned short)(u >> 16);
}
__device__ __forceinline__ float bf2f(unsigned short b) {
  return __uint_as_float(((unsigned)b) << 16);
}

// ---------------------------------------------------------------------------
// Weights f32 -> bf16 (4 x 64x64).
__global__ __launch_bounds__(256) void k_cvtW(const float* __restrict__ W1,
                                              const float* __restrict__ W2,
                                              const float* __restrict__ W3,
                                              const float* __restrict__ W4,
                                              unsigned short* __restrict__ Wb) {
  int i = blockIdx.x * 256 + threadIdx.x;  // 16*256 = 4096 exact
  Wb[i] = f2bf(W1[i]);
  Wb[4096 + i] = f2bf(W2[i]);
  Wb[8192 + i] = f2bf(W3[i]);
  Wb[12288 + i] = f2bf(W4[i]);
}

// x f32 [NN][64] -> bf16 row-major: one 128B line per row for the gather.
__global__ __launch_bounds__(256) void k_cvtX(const float* __restrict__ x,
                                              unsigned short* __restrict__ xb) {
  size_t i = ((size_t)blockIdx.x * 256 + threadIdx.x) * 8;  // 3125 blocks exact
  floatx4 v0 = *(const floatx4*)(x + i);
  floatx4 v1 = *(const floatx4*)(x + i + 4);
  short8 o;
  o[0] = (short)f2bf(v0.x); o[1] = (short)f2bf(v0.y);
  o[2] = (short)f2bf(v0.z); o[3] = (short)f2bf(v0.w);
  o[4] = (short)f2bf(v1.x); o[5] = (short)f2bf(v1.y);
  o[6] = (short)f2bf(v1.z); o[7] = (short)f2bf(v1.w);
  *(short8*)(xb + i) = o;
}

// ---------------------------------------------------------------------------
// ELL build via bucket partition — NO global atomics (round-0 proven chain).
// Pass 1: per-(block,bucket) histogram.
__global__ __launch_bounds__(256) void k_phist(const int* __restrict__ dst,
                                               int* __restrict__ blockHist) {
  __shared__ int h[NB];
  h[threadIdx.x] = 0;
  __syncthreads();
  int base = blockIdx.x * 2048;
#pragma unroll
  for (int i = 0; i < 8; i++) {
    int e = base + i * 256 + threadIdx.x;
    if (e < NE) atomicAdd(&h[dst[e] / BSZ], 1);
  }
  __syncthreads();
  blockHist[blockIdx.x * NB + threadIdx.x] = h[threadIdx.x];
}

// Pass 2: per-bucket exclusive scan over the EB block counts.
__global__ __launch_bounds__(1024) void k_colscan(const int* __restrict__ blockHist,
                                                  int* __restrict__ offsL,
                                                  int* __restrict__ colTot) {
  __shared__ int sh[1024];
  int c = blockIdx.x, t = threadIdx.x;
  int v = (t < EB) ? blockHist[t * NB + c] : 0;
  sh[t] = v;
  __syncthreads();
  for (int off = 1; off < 1024; off <<= 1) {
    int u = (t >= off) ? sh[t - off] : 0;
    __syncthreads();
    sh[t] += u;
    __syncthreads();
  }
  if (t < EB) offsL[t * NB + c] = sh[t] - v;  // exclusive within column
  if (t == EB - 1) colTot[c] = sh[t];
}

// Pass 3: exclusive scan of the 256 bucket totals -> bucket bases.
__global__ __launch_bounds__(256) void k_basescan(const int* __restrict__ colTot,
                                                  int* __restrict__ base) {
  __shared__ int sh[256];
  int t = threadIdx.x;
  int v = colTot[t];
  sh[t] = v;
  __syncthreads();
  for (int off = 1; off < 256; off <<= 1) {
    int u = (t >= off) ? sh[t - off] : 0;
    __syncthreads();
    sh[t] += u;
    __syncthreads();
  }
  base[t] = sh[t] - v;
  if (t == 255) base[256] = sh[255];
}

// Pass 4: scatter (src,dst) into bucket-partitioned array; rank via LDS atomic.
__global__ __launch_bounds__(256) void k_escat(const int* __restrict__ src,
                                               const int* __restrict__ dst,
                                               const int* __restrict__ offsL,
                                               const int* __restrict__ base,
                                               int2* __restrict__ ed) {
  __shared__ int h[NB];
  h[threadIdx.x] = 0;
  __syncthreads();
  int eb = blockIdx.x * 2048;
  const int* ofs = offsL + blockIdx.x * NB;
#pragma unroll
  for (int i = 0; i < 8; i++) {
    int e = eb + i * 256 + threadIdx.x;
    if (e < NE) {
      int d = dst[e];
      int c = d / BSZ;
      int r = atomicAdd(&h[c], 1);
      ed[base[c] + ofs[c] + r] = make_int2(src[e], d);
    }
  }
}

// Pass 5: one block per bucket; RANGE-SORTED ELL rows (slots grouped by
// src/RSZ in ascending range order) + packed capped boundaries rs[n]:
// byte k = min(cumulative count through range k, 64). Two passes over the
// bucket's edges with per-(node,range) LDS counters.
__global__ __launch_bounds__(256) void k_ellfill(const int2* __restrict__ ed,
                                                 const int* __restrict__ base,
                                                 int* __restrict__ ell,
                                                 unsigned long long* __restrict__ rs) {
  __shared__ int cnt[BSZ * NRG];  // 12512 B
  __shared__ int cur[BSZ * NRG];  // 12512 B
  int c = blockIdx.x;
  for (int i = threadIdx.x; i < BSZ * NRG; i += 256) cnt[i] = 0;
  __syncthreads();
  int lo = base[c], hi = base[c + 1];
  int n0 = c * BSZ;
  for (int e = lo + threadIdx.x; e < hi; e += 256) {
    int2 sd = ed[e];
    int k = (unsigned)sd.x / RSZ;
    atomicAdd(&cnt[(sd.y - n0) * NRG + k], 1);
  }
  __syncthreads();
  for (int i = threadIdx.x; i < BSZ; i += 256) {
    int n = n0 + i;
    if (n >= NN) continue;
    int run = 0;
    unsigned long long pk = 0;
#pragma unroll
    for (int k = 0; k < NRG; k++) {
      cur[i * NRG + k] = run;  // uncapped segment start
      run += cnt[i * NRG + k];
      int capped = run > 64 ? 64 : run;
      pk |= ((unsigned long long)(unsigned)capped) << (8 * k);
    }
    rs[n] = pk;
  }
  __syncthreads();
  for (int e = lo + threadIdx.x; e < hi; e += 256) {
    int2 sd = ed[e];
    int k = (unsigned)sd.x / RSZ;
    int slot = atomicAdd(&cur[(sd.y - n0) * NRG + k], 1);
    if (slot < 64) ell[(size_t)sd.y * 64 + slot] = sd.x;
  }
}

// ---------------------------------------------------------------------------
// Persistent range-phased gather. Grid 1563 blocks x 4 waves = 6252 waves —
// (nearly) all co-resident at <=85 VGPR, so all blocks sweep src ranges
// 0..7 in wall-clock lockstep: at any instant the live working set is ~1-2
// ranges (1.6-3.2 MB bf16) per XCD L2 instead of the full 12.8 MB. Each
// block owns 64 nodes; 32 lanes/node (2 feats each), f32 register accum.
// agg[n] = (1+eps)*pre(X[n]) + sum_{s in N(n)} pre(X[s]), bf16 row-major.
// MODE1: BN1 affine factored out: agg = A*(es*v + sum) + B*(es + deg).
template <int MODE>
__global__ __launch_bounds__(256, 6) void k_gat(
    const unsigned short* __restrict__ X,
    const unsigned long long* __restrict__ rs,
    const int* __restrict__ ell,
    const float* __restrict__ eps, const float* __restrict__ AB,
    unsigned short* __restrict__ agg) {
  const int s = threadIdx.x >> 5;          // node slot 0..7
  const int fo = (threadIdx.x & 31) * 2;   // feature pair
  const int nb = blockIdx.x * 64;
  const float es = 1.0f + eps[0];
  float a[8][2];
  unsigned long long bb[8];
#pragma unroll
  for (int g = 0; g < 8; g++) {
    int n = nb + g * 8 + s;
    if (n < NN) {
      ushort2 u = *(const ushort2*)(X + (size_t)n * 64 + fo);
      a[g][0] = es * bf2f(u.x);
      a[g][1] = es * bf2f(u.y);
      bb[g] = rs[n];
    } else {
      a[g][0] = 0.0f; a[g][1] = 0.0f; bb[g] = 0ULL;
    }
  }
  for (int k = 0; k < NRG; k++) {
#pragma unroll
    for (int g = 0; g < 8; g++) {
      int st = k ? (int)((bb[g] >> (8 * (k - 1))) & 255u) : 0;
      int en = (int)((bb[g] >> (8 * k)) & 255u);
      const int* row = ell + (size_t)(nb + g * 8 + s) * 64;
      int j = st;
      for (; j + 2 <= en; j += 2) {
        int s0 = row[j], s1 = row[j + 1];
        ushort2 u0 = *(const ushort2*)(X + (size_t)s0 * 64 + fo);
        ushort2 u1 = *(const ushort2*)(X + (size_t)s1 * 64 + fo);
        a[g][0] += bf2f(u0.x) + bf2f(u1.x);
        a[g][1] += bf2f(u0.y) + bf2f(u1.y);
      }
      if (j < en) {
        int s0 = row[j];
        ushort2 u0 = *(const ushort2*)(X + (size_t)s0 * 64 + fo);
        a[g][0] += bf2f(u0.x);
        a[g][1] += bf2f(u0.y);
      }
    }
  }
  float A0 = 1.0f, A1 = 1.0f, B0 = 0.0f, B1 = 0.0f;
  if (MODE) { A0 = AB[fo]; A1 = AB[fo + 1]; B0 = AB[64 + fo]; B1 = AB[64 + fo + 1]; }
#pragma unroll
  for (int g = 0; g < 8; g++) {
    int n = nb + g * 8 + s;
    if (n >= NN) continue;
    float r0 = a[g][0], r1 = a[g][1];
    if (MODE) {
      float w = es + (float)((unsigned)(bb[g] >> 56) & 255u);  // capped deg
      r0 = fmaf(r0, A0, w * B0);
      r1 = fmaf(r1, A1, w * B1);
    }
    ushort2 o;
    o.x = f2bf(r0);
    o.y = f2bf(r1);
    *(ushort2*)(agg + (size_t)n * 64 + fo) = o;
  }
}

// ---------------------------------------------------------------------------
// h2 = relu(relu(agg@Wa+ba)@Wb+bb) via bf16 MFMA 16x16x32; BN stats to f64.
// agg and h2 are row-major bf16 [NN][64].
__global__ __launch_bounds__(256) void k_mlp_mfma(
    const unsigned short* __restrict__ agg, const unsigned short* __restrict__ Wab,
    const float* __restrict__ ba, const float* __restrict__ bb,
    unsigned short* __restrict__ h2, double* __restrict__ stats) {
  const int l = threadIdx.x & 63;
  const int wv = threadIdx.x >> 6;
  const int l16 = l & 15, quad = l >> 4;

  short8 wfa[4][2], wfb[4][2];
#pragma unroll
  for (int c = 0; c < 4; c++)
#pragma unroll
    for (int t = 0; t < 2; t++)
#pragma unroll
      for (int j = 0; j < 8; j++) {
        int k = t * 32 + quad * 8 + j, nn = c * 16 + l16;
        wfa[c][t][j] = (short)Wab[k * 64 + nn];
        wfb[c][t][j] = (short)Wab[4096 + k * 64 + nn];
      }
  float bia[4], bib[4];
#pragma unroll
  for (int c = 0; c < 4; c++) { bia[c] = ba[c * 16 + l16]; bib[c] = bb[c * 16 + l16]; }

  __shared__ float Hs[4][16][68];
  __shared__ float sS[4][64], sQ[4][64];
  float ssum[4] = {0, 0, 0, 0}, ssq[4] = {0, 0, 0, 0};

  const int totw = gridDim.x * 4;
  for (int tile = blockIdx.x * 4 + wv; tile < NN / 16; tile += totw) {
    const int r0 = tile * 16;
    const unsigned short* ap = agg + (size_t)(r0 + l16) * 64 + quad * 8;
    short8 a0 = *(const short8*)ap;
    short8 a1 = *(const short8*)(ap + 32);
#pragma unroll
    for (int c = 0; c < 4; c++) {
      floatx4 acc = {0.f, 0.f, 0.f, 0.f};
      acc = __builtin_amdgcn_mfma_f32_16x16x32_bf16(a0, wfa[c][0], acc, 0, 0, 0);
      acc = __builtin_amdgcn_mfma_f32_16x16x32_bf16(a1, wfa[c][1], acc, 0, 0, 0);
#pragma unroll
      for (int r = 0; r < 4; r++)
        Hs[wv][quad * 4 + r][c * 16 + l16] = fmaxf(acc[r] + bia[c], 0.0f);
    }
    short8 a20, a21;
#pragma unroll
    for (int j = 0; j < 8; j++) {
      a20[j] = (short)f2bf(Hs[wv][l16][quad * 8 + j]);
      a21[j] = (short)f2bf(Hs[wv][l16][32 + quad * 8 + j]);
    }
#pragma unroll
    for (int c = 0; c < 4; c++) {
      floatx4 acc = {0.f, 0.f, 0.f, 0.f};
      acc = __builtin_amdgcn_mfma_f32_16x16x32_bf16(a20, wfb[c][0], acc, 0, 0, 0);
      acc = __builtin_amdgcn_mfma_f32_16x16x32_bf16(a21, wfb[c][1], acc, 0, 0, 0);
#pragma unroll
      for (int r = 0; r < 4; r++) {
        float v = fmaxf(acc[r] + bib[c], 0.0f);
        h2[(size_t)(r0 + quad * 4 + r) * 64 + c * 16 + l16] = f2bf(v);
        ssum[c] += v;
        ssq[c] += v * v;
      }
    }
  }
#pragma unroll
  for (int c = 0; c < 4; c++) {
    float s = ssum[c], q = ssq[c];
    s += __shfl_xor(s, 16, 64); s += __shfl_xor(s, 32, 64);
    q += __shfl_xor(q, 16, 64); q += __shfl_xor(q, 32, 64);
    if (quad == 0) { sS[wv][c * 16 + l16] = s; sQ[wv][c * 16 + l16] = q; }
  }
  __syncthreads();
  if (threadIdx.x < 64) {
    int ff = threadIdx.x;
    float s = sS[0][ff] + sS[1][ff] + sS[2][ff] + sS[3][ff];
    float q = sQ[0][ff] + sQ[1][ff] + sQ[2][ff] + sQ[3][ff];
    unsafeAtomicAdd(&stats[ff], (double)s);
    unsafeAtomicAdd(&stats[64 + ff], (double)q);
  }
}

// ---------------------------------------------------------------------------
// stats -> per-feature affine A (scale), B (shift): out = h*A + B
__global__ void k_bnfin(const double* __restrict__ stats, const float* __restrict__ gam,
                        const float* __restrict__ bet, float* __restrict__ AB) {
  int f = threadIdx.x;  // 64 threads
  double mean = stats[f] * (1.0 / NN);
  double var = stats[64 + f] * (1.0 / NN) - mean * mean;
  if (var < 0.0) var = 0.0;
  float rstd = (float)(1.0 / sqrt(var + 1e-5));
  float A = gam[f] * rstd;
  float B = bet[f] - (float)mean * A;
  AB[f] = A;
  AB[64 + f] = B;
}

// ---------------------------------------------------------------------------
// h = BN2(h2); out[0:N*64] = h; out[N*64:] = log_softmax(h). h2 row-major.
__global__ __launch_bounds__(256) void k_out(const unsigned short* __restrict__ h2,
                                             const float* __restrict__ AB,
                                             float* __restrict__ out) {
  int f = threadIdx.x & 63;
  int n = blockIdx.x * 4 + (threadIdx.x >> 6);  // 25000*4 = NN exact
  float v = bf2f(h2[(size_t)n * 64 + f]);
  float h = fmaf(v, AB[f], AB[64 + f]);
  float m = h;
#pragma unroll
  for (int off = 32; off; off >>= 1) m = fmaxf(m, __shfl_xor(m, off, 64));
  float e = expf(h - m);
  float ssum = e;
#pragma unroll
  for (int off = 32; off; off >>= 1) ssum += __shfl_xor(ssum, off, 64);
  float lsm = (h - m) - logf(ssum);
  out[(size_t)n * 64 + f] = h;
  out[(size_t)NN * 64 + (size_t)n * 64 + f] = lsm;
}

// ---------------------------------------------------------------------------
extern "C" void kernel_launch(void* const* d_in, const int* in_sizes, int n_in,
                              void* d_out, int out_size, void* d_ws, size_t ws_size,
                              hipStream_t stream) {
  const float* x = (const float*)d_in[0];
  const int* ei = (const int*)d_in[1];  // [2, E] as int32
  const float* W1 = (const float*)d_in[2];
  const float* b1 = (const float*)d_in[3];
  const float* W2 = (const float*)d_in[4];
  const float* b2 = (const float*)d_in[5];
  const float* g1 = (const float*)d_in[6];
  const float* bt1 = (const float*)d_in[7];
  const float* e1 = (const float*)d_in[8];
  const float* W3 = (const float*)d_in[9];
  const float* b3 = (const float*)d_in[10];
  const float* W4 = (const float*)d_in[11];
  const float* b4 = (const float*)d_in[12];
  const float* g2 = (const float*)d_in[13];
  const float* bt2 = (const float*)d_in[14];
  const float* e2 = (const float*)d_in[15];
  const int* src = ei;
  const int* dst = ei + NE;

  char* ws = (char*)d_ws;
  // 65.64 MB total (<= 66.04 MB proven safe). Aliases: ed dies after
  // k_ellfill -> aggb reuses it; blockHist dies after k_colscan -> rs.
  int* ell = (int*)(ws);                                   // [NN][64] int, 25.6 MB
  int2* ed = (int2*)(ws + 25600000);                       // 12.8 MB bucketed edges
  unsigned short* aggb = (unsigned short*)(ws + 25600000); // alias over ed
  unsigned short* xb = (unsigned short*)(ws + 38400000);   // 12.8 MB bf16 [NN][64]
  unsigned short* h2b = (unsigned short*)(ws + 51200000);  // 12.8 MB bf16 [NN][64]
  int* blockHist = (int*)(ws + 64000000);                  // 782*256 ints
  unsigned long long* rs = (unsigned long long*)(ws + 64000000);  // alias, 800 KB
  int* offsL = (int*)(ws + 64800768);                      // 782*256 ints
  int* colTot = (int*)(ws + 65601536);                     // 256 ints
  int* base = (int*)(ws + 65602560);                       // 257 ints (pad)
  double* st1 = (double*)(ws + 65603600);                  // 128 f64
  double* st2 = (double*)(ws + 65604624);                  // 128 f64
  float* AB1 = (float*)(ws + 65605648);                    // 128 f32
  float* AB2 = (float*)(ws + 65606160);                    // 128 f32
  unsigned short* Wbb = (unsigned short*)(ws + 65606672);  // 4*4096 bf16
  float* out = (float*)d_out;

  hipMemsetAsync(ws + 65603600, 0, 2048, stream);  // zero st1+st2

  k_cvtW<<<16, 256, 0, stream>>>(W1, W2, W3, W4, Wbb);
  k_cvtX<<<3125, 256, 0, stream>>>(x, xb);

  // --- range-sorted ELL build (no global atomics) ---
  k_phist<<<EB, 256, 0, stream>>>(dst, blockHist);
  k_colscan<<<NB, 1024, 0, stream>>>(blockHist, offsL, colTot);
  k_basescan<<<1, 256, 0, stream>>>(colTot, base);
  k_escat<<<EB, 256, 0, stream>>>(src, dst, offsL, base, ed);
  k_ellfill<<<NB, 256, 0, stream>>>(ed, base, ell, rs);

  // --- Layer 1 ---
  k_gat<0><<<1563, 256, 0, stream>>>(xb, rs, ell, e1, nullptr, aggb);
  k_mlp_mfma<<<782, 256, 0, stream>>>(aggb, Wbb, b1, b2, h2b, st1);
  k_bnfin<<<1, 64, 0, stream>>>(st1, g1, bt1, AB1);
  // --- Layer 2 (BN1 affine factored into the gather epilogue) ---
  k_gat<1><<<1563, 256, 0, stream>>>(h2b, rs, ell, e2, AB1, aggb);
  k_mlp_mfma<<<782, 256, 0, stream>>>(aggb, Wbb + 8192, b3, b4, h2b, st2);
  k_bnfin<<<1, 64, 0, stream>>>(st2, g2, bt2, AB2);
  // --- Epilogue: BN2 + log_softmax ---
  k_out<<<NN / 4, 256, 0, stream>>>(h2b, AB2, out);
}

// Round 7
// 447.495 us; speedup vs baseline: 9.7732x; 9.7732x over previous
//
#include <hip/hip_runtime.h>

#define NN 100000
#define NE 1600000
#define NB 256    // dst buckets
#define BSZ 391   // nodes per bucket (255*391=99705; bucket 255 holds 295)
#define EB 782    // edge blocks of 2048
#define NRG 8     // src ranges for phased gather
#define RSZ 12500 // range size (8*12500 = NN exact)

typedef __attribute__((ext_vector_type(8))) short short8;
typedef __attribute__((ext_vector_type(4))) float floatx4;

__device__ __forceinline__ unsigned short f2bf(float f) {
  unsigned u = __float_as_uint(f);
  u += 0x7fffu + ((u >> 16) & 1u);  // RNE
  return (unsigned short)(u >> 16);
}
__device__ __forceinline__ float bf2f(unsigned short b) {
  return __uint_as_float(((unsigned)b) << 16);
}

// ---------------------------------------------------------------------------
// Weights f32 -> bf16 (4 x 64x64).
__global__ __launch_bounds__(256) void k_cvtW(const float* __restrict__ W1,
                                              const float* __restrict__ W2,
                                              const float* __restrict__ W3,
                                              const float* __restrict__ W4,
                                              unsigned short* __restrict__ Wb) {
  int i = blockIdx.x * 256 + threadIdx.x;  // 16*256 = 4096 exact
  Wb[i] = f2bf(W1[i]);
  Wb[4096 + i] = f2bf(W2[i]);
  Wb[8192 + i] = f2bf(W3[i]);
  Wb[12288 + i] = f2bf(W4[i]);
}

// x f32 [NN][64] -> bf16 row-major: one 128B line per row for the gather.
__global__ __launch_bounds__(256) void k_cvtX(const float* __restrict__ x,
                                              unsigned short* __restrict__ xb) {
  size_t i = ((size_t)blockIdx.x * 256 + threadIdx.x) * 8;  // 3125 blocks exact
  floatx4 v0 = *(const floatx4*)(x + i);
  floatx4 v1 = *(const floatx4*)(x + i + 4);
  short8 o;
  o[0] = (short)f2bf(v0.x); o[1] = (short)f2bf(v0.y);
  o[2] = (short)f2bf(v0.z); o[3] = (short)f2bf(v0.w);
  o[4] = (short)f2bf(v1.x); o[5] = (short)f2bf(v1.y);
  o[6] = (short)f2bf(v1.z); o[7] = (short)f2bf(v1.w);
  *(short8*)(xb + i) = o;
}

// ---------------------------------------------------------------------------
// ELL build via bucket partition — NO global atomics (round-0 proven chain).
// Pass 1: per-(block,bucket) histogram.
__global__ __launch_bounds__(256) void k_phist(const int* __restrict__ dst,
                                               int* __restrict__ blockHist) {
  __shared__ int h[NB];
  h[threadIdx.x] = 0;
  __syncthreads();
  int base = blockIdx.x * 2048;
#pragma unroll
  for (int i = 0; i < 8; i++) {
    int e = base + i * 256 + threadIdx.x;
    if (e < NE) atomicAdd(&h[dst[e] / BSZ], 1);
  }
  __syncthreads();
  blockHist[blockIdx.x * NB + threadIdx.x] = h[threadIdx.x];
}

// Pass 2: per-bucket exclusive scan over the EB block counts.
__global__ __launch_bounds__(1024) void k_colscan(const int* __restrict__ blockHist,
                                                  int* __restrict__ offsL,
                                                  int* __restrict__ colTot) {
  __shared__ int sh[1024];
  int c = blockIdx.x, t = threadIdx.x;
  int v = (t < EB) ? blockHist[t * NB + c] : 0;
  sh[t] = v;
  __syncthreads();
  for (int off = 1; off < 1024; off <<= 1) {
    int u = (t >= off) ? sh[t - off] : 0;
    __syncthreads();
    sh[t] += u;
    __syncthreads();
  }
  if (t < EB) offsL[t * NB + c] = sh[t] - v;  // exclusive within column
  if (t == EB - 1) colTot[c] = sh[t];
}

// Pass 3: exclusive scan of the 256 bucket totals -> bucket bases.
__global__ __launch_bounds__(256) void k_basescan(const int* __restrict__ colTot,
                                                  int* __restrict__ base) {
  __shared__ int sh[256];
  int t = threadIdx.x;
  int v = colTot[t];
  sh[t] = v;
  __syncthreads();
  for (int off = 1; off < 256; off <<= 1) {
    int u = (t >= off) ? sh[t - off] : 0;
    __syncthreads();
    sh[t] += u;
    __syncthreads();
  }
  base[t] = sh[t] - v;
  if (t == 255) base[256] = sh[255];
}

// Pass 4: scatter (src,dst) into bucket-partitioned array; rank via LDS atomic.
__global__ __launch_bounds__(256) void k_escat(const int* __restrict__ src,
                                               const int* __restrict__ dst,
                                               const int* __restrict__ offsL,
                                               const int* __restrict__ base,
                                               int2* __restrict__ ed) {
  __shared__ int h[NB];
  h[threadIdx.x] = 0;
  __syncthreads();
  int eb = blockIdx.x * 2048;
  const int* ofs = offsL + blockIdx.x * NB;
#pragma unroll
  for (int i = 0; i < 8; i++) {
    int e = eb + i * 256 + threadIdx.x;
    if (e < NE) {
      int d = dst[e];
      int c = d / BSZ;
      int r = atomicAdd(&h[c], 1);
      ed[base[c] + ofs[c] + r] = make_int2(src[e], d);
    }
  }
}

// Pass 5: one block per bucket; RANGE-SORTED ELL rows (slots grouped by
// src/RSZ ascending) + packed capped boundaries rs[n]: byte k =
// min(cumulative count through range k, 64).
__global__ __launch_bounds__(256) void k_ellfill(const int2* __restrict__ ed,
                                                 const int* __restrict__ base,
                                                 int* __restrict__ ell,
                                                 unsigned long long* __restrict__ rs) {
  __shared__ int cnt[BSZ * NRG];  // 12512 B
  __shared__ int cur[BSZ * NRG];  // 12512 B
  int c = blockIdx.x;
  for (int i = threadIdx.x; i < BSZ * NRG; i += 256) cnt[i] = 0;
  __syncthreads();
  int lo = base[c], hi = base[c + 1];
  int n0 = c * BSZ;
  for (int e = lo + threadIdx.x; e < hi; e += 256) {
    int2 sd = ed[e];
    int k = (unsigned)sd.x / RSZ;
    atomicAdd(&cnt[(sd.y - n0) * NRG + k], 1);
  }
  __syncthreads();
  for (int i = threadIdx.x; i < BSZ; i += 256) {
    int n = n0 + i;
    if (n >= NN) continue;
    int run = 0;
    unsigned long long pk = 0;
#pragma unroll
    for (int k = 0; k < NRG; k++) {
      cur[i * NRG + k] = run;  // uncapped segment start
      run += cnt[i * NRG + k];
      int capped = run > 64 ? 64 : run;
      pk |= ((unsigned long long)(unsigned)capped) << (8 * k);
    }
    rs[n] = pk;
  }
  __syncthreads();
  for (int e = lo + threadIdx.x; e < hi; e += 256) {
    int2 sd = ed[e];
    int k = (unsigned)sd.x / RSZ;
    int slot = atomicAdd(&cur[(sd.y - n0) * NRG + k], 1);
    if (slot < 64) ell[(size_t)sd.y * 64 + slot] = sd.x;
  }
}

// ---------------------------------------------------------------------------
// Range-phased gather, LDS accumulators (rule #20: NO private arrays).
// Grid 1563 blocks x 4 waves, ~6 blocks/CU co-resident; all blocks sweep
// src ranges 0..7 with a barrier per phase, so the live X working set at
// any instant is ~1-2 ranges (1.6-3.2 MB bf16) per XCD L2 instead of the
// full 12.8 MB — neighbor reads become L2 hits. Each block owns 64 nodes;
// thread (s, lane) owns feature pair 2*lane of nodes {g*8+s}.
// agg[n] = (1+eps)*pre(X[n]) + sum_{s in N(n)} pre(X[s]), bf16 row-major.
// MODE1: BN1 affine factored out: agg = A*(es*v + sum) + B*(es + deg).
template <int MODE>
__global__ __launch_bounds__(256) void k_gat(
    const unsigned short* __restrict__ X,
    const unsigned long long* __restrict__ rs,
    const int* __restrict__ ell,
    const float* __restrict__ eps, const float* __restrict__ AB,
    unsigned short* __restrict__ agg) {
  __shared__ float acc[64][67];  // pad 67: 2-way lane aliasing only (free)
  __shared__ unsigned long long bbs[64];
  const int lane = threadIdx.x & 31;
  const int s = threadIdx.x >> 5;
  const int fo = lane * 2;
  const int nb = blockIdx.x * 64;
  const float es = 1.0f + eps[0];
  if (threadIdx.x < 64) {
    int n = nb + threadIdx.x;
    bbs[threadIdx.x] = (n < NN) ? rs[n] : 0ULL;
  }
#pragma unroll
  for (int g = 0; g < 8; g++) {
    int nl = g * 8 + s;
    int n = nb + nl;
    float v0 = 0.0f, v1 = 0.0f;
    if (n < NN) {
      unsigned up = __builtin_nontemporal_load(
          (const unsigned*)(X + (size_t)n * 64 + fo));
      v0 = es * bf2f((unsigned short)(up & 0xffffu));
      v1 = es * bf2f((unsigned short)(up >> 16));
    }
    acc[nl][fo] = v0;
    acc[nl][fo + 1] = v1;
  }
  __syncthreads();
  for (int k = 0; k < NRG; k++) {
    for (int g = 0; g < 8; g++) {
      int nl = g * 8 + s;
      int n = nb + nl;
      if (n >= NN) continue;
      unsigned long long b = bbs[nl];
      int st = k ? (int)((b >> (8 * (k - 1))) & 255u) : 0;
      int en = (int)((b >> (8 * k)) & 255u);
      if (st >= en) continue;
      const int* row = ell + (size_t)n * 64;
      float a0 = acc[nl][fo], a1 = acc[nl][fo + 1];
      int j = st;
      for (; j + 2 <= en; j += 2) {
        int s0 = row[j], s1 = row[j + 1];
        ushort2 u0 = *(const ushort2*)(X + (size_t)s0 * 64 + fo);
        ushort2 u1 = *(const ushort2*)(X + (size_t)s1 * 64 + fo);
        a0 += bf2f(u0.x) + bf2f(u1.x);
        a1 += bf2f(u0.y) + bf2f(u1.y);
      }
      if (j < en) {
        ushort2 u0 = *(const ushort2*)(X + (size_t)row[j] * 64 + fo);
        a0 += bf2f(u0.x);
        a1 += bf2f(u0.y);
      }
      acc[nl][fo] = a0;
      acc[nl][fo + 1] = a1;
    }
    __syncthreads();  // phase barrier: keeps ranges time-localized
  }
  float A0 = 1.0f, A1 = 1.0f, B0 = 0.0f, B1 = 0.0f;
  if (MODE) { A0 = AB[fo]; A1 = AB[fo + 1]; B0 = AB[64 + fo]; B1 = AB[64 + fo + 1]; }
#pragma unroll
  for (int g = 0; g < 8; g++) {
    int nl = g * 8 + s;
    int n = nb + nl;
    if (n >= NN) continue;
    float r0 = acc[nl][fo], r1 = acc[nl][fo + 1];
    if (MODE) {
      float w = es + (float)((unsigned)(bbs[nl] >> 56) & 255u);  // capped deg
      r0 = fmaf(r0, A0, w * B0);
      r1 = fmaf(r1, A1, w * B1);
    }
    unsigned o = (unsigned)f2bf(r0) | ((unsigned)f2bf(r1) << 16);
    __builtin_nontemporal_store(o, (unsigned*)(agg + (size_t)n * 64 + fo));
  }
}

// ---------------------------------------------------------------------------
// h2 = relu(relu(agg@Wa+ba)@Wb+bb) via bf16 MFMA 16x16x32; BN stats to f64.
// agg and h2 are row-major bf16 [NN][64].
__global__ __launch_bounds__(256) void k_mlp_mfma(
    const unsigned short* __restrict__ agg, const unsigned short* __restrict__ Wab,
    const float* __restrict__ ba, const float* __restrict__ bb,
    unsigned short* __restrict__ h2, double* __restrict__ stats) {
  const int l = threadIdx.x & 63;
  const int wv = threadIdx.x >> 6;
  const int l16 = l & 15, quad = l >> 4;

  short8 wfa[4][2], wfb[4][2];
#pragma unroll
  for (int c = 0; c < 4; c++)
#pragma unroll
    for (int t = 0; t < 2; t++)
#pragma unroll
      for (int j = 0; j < 8; j++) {
        int k = t * 32 + quad * 8 + j, nn = c * 16 + l16;
        wfa[c][t][j] = (short)Wab[k * 64 + nn];
        wfb[c][t][j] = (short)Wab[4096 + k * 64 + nn];
      }
  float bia[4], bib[4];
#pragma unroll
  for (int c = 0; c < 4; c++) { bia[c] = ba[c * 16 + l16]; bib[c] = bb[c * 16 + l16]; }

  __shared__ float Hs[4][16][68];
  __shared__ float sS[4][64], sQ[4][64];
  float ssum[4] = {0, 0, 0, 0}, ssq[4] = {0, 0, 0, 0};

  const int totw = gridDim.x * 4;
  for (int tile = blockIdx.x * 4 + wv; tile < NN / 16; tile += totw) {
    const int r0 = tile * 16;
    const unsigned short* ap = agg + (size_t)(r0 + l16) * 64 + quad * 8;
    short8 a0 = *(const short8*)ap;
    short8 a1 = *(const short8*)(ap + 32);
#pragma unroll
    for (int c = 0; c < 4; c++) {
      floatx4 acc = {0.f, 0.f, 0.f, 0.f};
      acc = __builtin_amdgcn_mfma_f32_16x16x32_bf16(a0, wfa[c][0], acc, 0, 0, 0);
      acc = __builtin_amdgcn_mfma_f32_16x16x32_bf16(a1, wfa[c][1], acc, 0, 0, 0);
#pragma unroll
      for (int r = 0; r < 4; r++)
        Hs[wv][quad * 4 + r][c * 16 + l16] = fmaxf(acc[r] + bia[c], 0.0f);
    }
    short8 a20, a21;
#pragma unroll
    for (int j = 0; j < 8; j++) {
      a20[j] = (short)f2bf(Hs[wv][l16][quad * 8 + j]);
      a21[j] = (short)f2bf(Hs[wv][l16][32 + quad * 8 + j]);
    }
#pragma unroll
    for (int c = 0; c < 4; c++) {
      floatx4 acc = {0.f, 0.f, 0.f, 0.f};
      acc = __builtin_amdgcn_mfma_f32_16x16x32_bf16(a20, wfb[c][0], acc, 0, 0, 0);
      acc = __builtin_amdgcn_mfma_f32_16x16x32_bf16(a21, wfb[c][1], acc, 0, 0, 0);
#pragma unroll
      for (int r = 0; r < 4; r++) {
        float v = fmaxf(acc[r] + bib[c], 0.0f);
        h2[(size_t)(r0 + quad * 4 + r) * 64 + c * 16 + l16] = f2bf(v);
        ssum[c] += v;
        ssq[c] += v * v;
      }
    }
  }
#pragma unroll
  for (int c = 0; c < 4; c++) {
    float s = ssum[c], q = ssq[c];
    s += __shfl_xor(s, 16, 64); s += __shfl_xor(s, 32, 64);
    q += __shfl_xor(q, 16, 64); q += __shfl_xor(q, 32, 64);
    if (quad == 0) { sS[wv][c * 16 + l16] = s; sQ[wv][c * 16 + l16] = q; }
  }
  __syncthreads();
  if (threadIdx.x < 64) {
    int ff = threadIdx.x;
    float s = sS[0][ff] + sS[1][ff] + sS[2][ff] + sS[3][ff];
    float q = sQ[0][ff] + sQ[1][ff] + sQ[2][ff] + sQ[3][ff];
    unsafeAtomicAdd(&stats[ff], (double)s);
    unsafeAtomicAdd(&stats[64 + ff], (double)q);
  }
}

// ---------------------------------------------------------------------------
// stats -> per-feature affine A (scale), B (shift): out = h*A + B
__global__ void k_bnfin(const double* __restrict__ stats, const float* __restrict__ gam,
                        const float* __restrict__ bet, float* __restrict__ AB) {
  int f = threadIdx.x;  // 64 threads
  double mean = stats[f] * (1.0 / NN);
  double var = stats[64 + f] * (1.0 / NN) - mean * mean;
  if (var < 0.0) var = 0.0;
  float rstd = (float)(1.0 / sqrt(var + 1e-5));
  float A = gam[f] * rstd;
  float B = bet[f] - (float)mean * A;
  AB[f] = A;
  AB[64 + f] = B;
}

// ---------------------------------------------------------------------------
// h = BN2(h2); out[0:N*64] = h; out[N*64:] = log_softmax(h). h2 row-major.
// 8 nodes/block, 32 lanes/node, 2 feats/lane. GRID MUST BE NN/8 = 12500.
__global__ __launch_bounds__(256) void k_out(const unsigned short* __restrict__ h2,
                                             const float* __restrict__ AB,
                                             float* __restrict__ out) {
  int lane = threadIdx.x & 31;
  int fo = lane * 2;
  int n = blockIdx.x * 8 + (threadIdx.x >> 5);  // 12500 blocks * 8 = NN exact
  ushort2 u = *(const ushort2*)(h2 + (size_t)n * 64 + fo);
  float h0 = fmaf(bf2f(u.x), AB[fo], AB[64 + fo]);
  float h1 = fmaf(bf2f(u.y), AB[fo + 1], AB[64 + fo + 1]);
  float m = fmaxf(h0, h1);
#pragma unroll
  for (int off = 16; off; off >>= 1) m = fmaxf(m, __shfl_xor(m, off, 32));
  float e0 = expf(h0 - m), e1 = expf(h1 - m);
  float ss = e0 + e1;
#pragma unroll
  for (int off = 16; off; off >>= 1) ss += __shfl_xor(ss, off, 32);
  float ls = logf(ss);
  float2 ho, lo;
  ho.x = h0; ho.y = h1;
  lo.x = (h0 - m) - ls; lo.y = (h1 - m) - ls;
  *(float2*)(out + (size_t)n * 64 + fo) = ho;
  *(float2*)(out + (size_t)NN * 64 + (size_t)n * 64 + fo) = lo;
}

// ---------------------------------------------------------------------------
extern "C" void kernel_launch(void* const* d_in, const int* in_sizes, int n_in,
                              void* d_out, int out_size, void* d_ws, size_t ws_size,
                              hipStream_t stream) {
  const float* x = (const float*)d_in[0];
  const int* ei = (const int*)d_in[1];  // [2, E] as int32
  const float* W1 = (const float*)d_in[2];
  const float* b1 = (const float*)d_in[3];
  const float* W2 = (const float*)d_in[4];
  const float* b2 = (const float*)d_in[5];
  const float* g1 = (const float*)d_in[6];
  const float* bt1 = (const float*)d_in[7];
  const float* e1 = (const float*)d_in[8];
  const float* W3 = (const float*)d_in[9];
  const float* b3 = (const float*)d_in[10];
  const float* W4 = (const float*)d_in[11];
  const float* b4 = (const float*)d_in[12];
  const float* g2 = (const float*)d_in[13];
  const float* bt2 = (const float*)d_in[14];
  const float* e2 = (const float*)d_in[15];
  const int* src = ei;
  const int* dst = ei + NE;

  char* ws = (char*)d_ws;
  // 65.64 MB total. Aliases: ed dies after k_ellfill -> aggb reuses it;
  // blockHist dies after k_colscan -> rs.
  int* ell = (int*)(ws);                                   // [NN][64] int, 25.6 MB
  int2* ed = (int2*)(ws + 25600000);                       // 12.8 MB bucketed edges
  unsigned short* aggb = (unsigned short*)(ws + 25600000); // alias over ed
  unsigned short* xb = (unsigned short*)(ws + 38400000);   // 12.8 MB bf16 [NN][64]
  unsigned short* h2b = (unsigned short*)(ws + 51200000);  // 12.8 MB bf16 [NN][64]
  int* blockHist = (int*)(ws + 64000000);                  // 782*256 ints
  unsigned long long* rs = (unsigned long long*)(ws + 64000000);  // alias, 800 KB
  int* offsL = (int*)(ws + 64800768);                      // 782*256 ints
  int* colTot = (int*)(ws + 65601536);                     // 256 ints
  int* base = (int*)(ws + 65602560);                       // 257 ints (pad)
  double* st1 = (double*)(ws + 65603600);                  // 128 f64
  double* st2 = (double*)(ws + 65604624);                  // 128 f64
  float* AB1 = (float*)(ws + 65605648);                    // 128 f32
  float* AB2 = (float*)(ws + 65606160);                    // 128 f32
  unsigned short* Wbb = (unsigned short*)(ws + 65606672);  // 4*4096 bf16
  float* out = (float*)d_out;

  hipMemsetAsync(ws + 65603600, 0, 2048, stream);  // zero st1+st2

  k_cvtW<<<16, 256, 0, stream>>>(W1, W2, W3, W4, Wbb);
  k_cvtX<<<3125, 256, 0, stream>>>(x, xb);

  // --- range-sorted ELL build (no global atomics) ---
  k_phist<<<EB, 256, 0, stream>>>(dst, blockHist);
  k_colscan<<<NB, 1024, 0, stream>>>(blockHist, offsL, colTot);
  k_basescan<<<1, 256, 0, stream>>>(colTot, base);
  k_escat<<<EB, 256, 0, stream>>>(src, dst, offsL, base, ed);
  k_ellfill<<<NB, 256, 0, stream>>>(ed, base, ell, rs);

  // --- Layer 1 ---
  k_gat<0><<<1563, 256, 0, stream>>>(xb, rs, ell, e1, nullptr, aggb);
  k_mlp_mfma<<<782, 256, 0, stream>>>(aggb, Wbb, b1, b2, h2b, st1);
  k_bnfin<<<1, 64, 0, stream>>>(st1, g1, bt1, AB1);
  // --- Layer 2 (BN1 affine factored into the gather epilogue) ---
  k_gat<1><<<1563, 256, 0, stream>>>(h2b, rs, ell, e2, AB1, aggb);
  k_mlp_mfma<<<782, 256, 0, stream>>>(aggb, Wbb + 8192, b3, b4, h2b, st2);
  k_bnfin<<<1, 64, 0, stream>>>(st2, g2, bt2, AB2);
  // --- Epilogue: BN2 + log_softmax ---
  k_out<<<12500, 256, 0, stream>>>(h2b, AB2, out);
}